// Round 4
// baseline (1846.350 us; speedup 1.0000x reference)
//
#include <hip/hip_runtime.h>

typedef float2 cplx;

#define SPAT 524288          // 32*32*32*16
#define TWO_PI_16 0.39269908169872414f
#define TWO_PI_32 0.19634954084936207f

// ws layout (bytes)
#define H_OFF   0u
#define A_OFF   83886080u
#define BT_OFF  (83886080u + 31457280u)
#define CT_OFF  (83886080u + 31457280u + 7864320u)
#define FLAG_OFF (83886080u + 31457280u + 7864320u + 7864320u)
#define WS_NEED (FLAG_OFF + 64u)

__device__ __forceinline__ float bf2f(unsigned short s){
    union { unsigned int u; float f; } v; v.u = ((unsigned int)s) << 16; return v.f;
}
__device__ __forceinline__ unsigned short f2bf(float f){
    union { float ff; unsigned int u; } v; v.ff = f;
    unsigned int u = v.u;
    u += 0x7fffu + ((u >> 16) & 1u);   // round-to-nearest-even
    return (unsigned short)(u >> 16);
}
__device__ __forceinline__ cplx bf2c(unsigned int p){
    union { unsigned int u; float f; } a, b;
    a.u = p << 16; b.u = p & 0xffff0000u;
    cplx r; r.x = a.f; r.y = b.f; return r;
}
// runtime-dtype loads/stores (bf=1: bf16 storage, bf=0: fp32 storage)
__device__ __forceinline__ float LDR(const void* p, size_t i, int bf){
    return bf ? bf2f(((const unsigned short*)p)[i]) : ((const float*)p)[i];
}
__device__ __forceinline__ void STR(void* p, size_t i, float v, int bf){
    if (bf) ((unsigned short*)p)[i] = f2bf(v);
    else    ((float*)p)[i] = v;
}
__device__ __forceinline__ void cmadd(cplx& d, const cplx a, const cplx b){
    d.x = fmaf(a.x, b.x, d.x);
    d.x = fmaf(-a.y, b.y, d.x);
    d.y = fmaf(a.x, b.y, d.y);
    d.y = fmaf(a.y, b.x, d.y);
}
__device__ __forceinline__ int freqm(int m){ return m + ((m >> 3) << 4); } // 0..7 -> 0..7, 8..15 -> 24..31
__device__ __forceinline__ float gelu_f(float v){
    return 0.5f * v * (1.0f + erff(v * 0.7071067811865475f));
}

// ------------------------------------------------- dtype detector (1 block, 1 wave, no atomics)
// Even-indexed u16 halves of x: fp32 data -> random mantissa bits (~68% wild bf16
// exponents); bf16 data -> genuine ~N(0,1) values (~0%).
__global__ void k_detect(const unsigned short* __restrict__ x, int* __restrict__ flag){
    __shared__ int cnts[64];
    const int tid = threadIdx.x;
    int cnt = 0;
    for (int j = tid; j < 512; j += 64){
        unsigned short u = x[2 * j];
        unsigned int e = (u >> 7) & 0xFFu;
        if (e < 27u || e > 160u) cnt++;    // |bf16| outside [~1e-30, ~1e10] incl inf/nan/denorm
    }
    cnts[tid] = cnt;
    __syncthreads();
    if (tid == 0){
        int s = 0;
        for (int i = 0; i < 64; i++) s += cnts[i];
        flag[0] = (s > 64) ? 0 : 1;        // many wild exponents -> fp32
    }
}

// ---------------------------------------------------------------- fc0 lift
__global__ __launch_bounds__(256) void k_fc0(const int* __restrict__ flag,
                                             const void* __restrict__ x,
                                             const void* __restrict__ w,
                                             const void* __restrict__ bias,
                                             float* __restrict__ h){
    const int bf = flag[0];
    __shared__ float sw[100];
    __shared__ float sb[20];
    const int tid = threadIdx.x;
    if (tid < 100) sw[tid] = LDR(w, tid, bf);
    if (tid < 20)  sb[tid] = LDR(bias, tid, bf);
    __syncthreads();
    const int p = blockIdx.x * 256 + tid;          // 0 .. 1048575
    const int b = p >> 19;
    const int rem = p & (SPAT - 1);
    float xi[5];
    #pragma unroll
    for (int i = 0; i < 5; i++) xi[i] = LDR(x, (size_t)p * 5 + i, bf);
    const size_t ob = (size_t)b * 20 * SPAT + rem;
    #pragma unroll
    for (int c = 0; c < 20; c++){
        float acc = sb[c];
        #pragma unroll
        for (int i = 0; i < 5; i++) acc = fmaf(xi[i], sw[i * 20 + c], acc);
        h[ob + (size_t)c * SPAT] = acc;
    }
}

// ------------------------------------------------- forward T (rfft, 6 bins) + Z (16 bins)
// h[b,c,x,y,z,t] -> A[bc][mz(16)][k4(6)][x][y]
__global__ __launch_bounds__(256) void k_fwdTZ(const float* __restrict__ h, cplx* __restrict__ A){
    const int bc = blockIdx.z;           // 0..39
    const int x  = blockIdx.y;           // 0..31
    const int y0 = blockIdx.x << 3;      // y tile of 8
    __shared__ float sinp[8][32][17];
    __shared__ cplx  mid[8][193];
    __shared__ cplx  twT[6][16];
    __shared__ cplx  twZ[16][32];
    const int tid = threadIdx.x;
    for (int i = tid; i < 96; i += 256){
        int k = i >> 4, t = i & 15;
        float s, c; sincosf(-TWO_PI_16 * (float)((k * t) & 15), &s, &c);
        twT[k][t] = make_float2(c, s);
    }
    for (int i = tid; i < 512; i += 256){
        int m = i >> 5, z = i & 31;
        float s, c; sincosf(-TWO_PI_32 * (float)((freqm(m) * z) & 31), &s, &c);
        twZ[m][z] = make_float2(c, s);
    }
    const float* src = h + ((size_t)bc * 1024 + x * 32 + y0) * 512;
    for (int i = tid; i < 4096; i += 256){
        int line = i >> 9, zt = i & 511;
        sinp[line][zt >> 4][zt & 15] = src[i];
    }
    __syncthreads();
    #pragma unroll
    for (int r = 0; r < 6; r++){
        int idx = tid + (r << 8);
        int k4 = idx % 6;
        int zz = (idx / 6) & 31;
        int line = idx / 192;
        cplx acc = make_float2(0.f, 0.f);
        #pragma unroll
        for (int t = 0; t < 16; t++){
            float v = sinp[line][zz][t];
            acc.x = fmaf(v, twT[k4][t].x, acc.x);
            acc.y = fmaf(v, twT[k4][t].y, acc.y);
        }
        mid[line][zz * 6 + k4] = acc;
    }
    __syncthreads();
    #pragma unroll
    for (int r = 0; r < 3; r++){
        int idx = tid + (r << 8);
        int line = idx & 7;
        int mzk = idx >> 3;
        int k4 = mzk % 6;
        int mz = mzk / 6;
        cplx acc = make_float2(0.f, 0.f);
        #pragma unroll
        for (int zz = 0; zz < 32; zz++)
            cmadd(acc, mid[line][zz * 6 + k4], twZ[mz][zz]);
        A[((size_t)bc * 96 + mz * 6 + k4) * 1024 + x * 32 + y0 + line] = acc;
    }
}

// ------------------------------------------------- forward Y + X
// A[bc][mz][k4][x][y] -> Bt[b*20+c][mx][my][mz][k4]
__global__ __launch_bounds__(256) void k_fwdXY(const cplx* __restrict__ A, cplx* __restrict__ Bt){
    const int kh = blockIdx.x;
    const int mz = blockIdx.y;
    const int bc = blockIdx.z;
    __shared__ cplx inb[3][1057];
    __shared__ cplx midY[3][545];
    __shared__ cplx tw[16][32];
    const int tid = threadIdx.x;
    for (int i = tid; i < 512; i += 256){
        int m = i >> 5, p = i & 31;
        float s, c; sincosf(-TWO_PI_32 * (float)((freqm(m) * p) & 31), &s, &c);
        tw[m][p] = make_float2(c, s);
    }
    const cplx* src = A + ((size_t)bc * 96 + mz * 6 + kh * 3) * 1024;
    for (int i = tid; i < 3072; i += 256){
        int k = i >> 10, rem = i & 1023;
        inb[k][(rem >> 5) * 33 + (rem & 31)] = src[i];
    }
    __syncthreads();
    #pragma unroll
    for (int r = 0; r < 6; r++){
        int idx = tid + (r << 8);
        int k = idx % 3, t2 = idx / 3;
        int my = t2 & 15, xx = t2 >> 4;
        cplx acc = make_float2(0.f, 0.f);
        #pragma unroll
        for (int yy = 0; yy < 32; yy++) cmadd(acc, inb[k][xx * 33 + yy], tw[my][yy]);
        midY[k][xx * 17 + my] = acc;
    }
    __syncthreads();
    #pragma unroll
    for (int r = 0; r < 3; r++){
        int idx = tid + (r << 8);
        int k = idx % 3, t2 = idx / 3;
        int my = t2 & 15, mx = t2 >> 4;
        cplx acc = make_float2(0.f, 0.f);
        #pragma unroll
        for (int xx = 0; xx < 32; xx++) cmadd(acc, midY[k][xx * 17 + my], tw[mx][xx]);
        Bt[((size_t)bc * 256 + mx * 16 + my) * 96 + mz * 6 + kh * 3 + k] = acc;
    }
}

// ------------------------------------------------- per-mode channel mix (20x20 complex)
__global__ __launch_bounds__(192) void k_mix(const int* __restrict__ flag,
                                             const cplx* __restrict__ Bt,
                                             const void* __restrict__ sw, size_t loff,
                                             cplx* __restrict__ Ct){
    const int bf = flag[0];
    const int j2 = blockIdx.x, j1 = blockIdx.y, oct = blockIdx.z;
    const int xh = oct >> 2, yh = (oct >> 1) & 1, zh = oct & 1;
    const int mx = xh * 8 + j1, my = yh * 8 + j2;
    __shared__ cplx inS[40][48];
    const int tid = threadIdx.x;
    for (int idx = tid; idx < 1920; idx += 192){
        int m = idx % 48, row = idx / 48;
        inS[row][m] = Bt[((size_t)row * 256 + mx * 16 + my) * 96 + zh * 48 + m];
    }
    __syncthreads();
    const int m = tid % 48, og = tid / 48;
    cplx acc[5][2];
    #pragma unroll
    for (int jo = 0; jo < 5; jo++){
        acc[jo][0] = make_float2(0.f, 0.f);
        acc[jo][1] = make_float2(0.f, 0.f);
    }
    const size_t base0 = loff + (size_t)(oct * 20) * 20 * 3072
                              + (size_t)(og * 5) * 3072 + (j1 * 8 + j2) * 48 + m;
    if (bf){
        const unsigned int* swp = (const unsigned int*)sw;
        for (int i = 0; i < 20; i++){
            cplx a0 = inS[i][m];
            cplx a1 = inS[20 + i][m];
            const unsigned int* wr = swp + base0 + (size_t)i * 20 * 3072;
            #pragma unroll
            for (int jo = 0; jo < 5; jo++){
                cplx w = bf2c(wr[(size_t)jo * 3072]);
                cmadd(acc[jo][0], a0, w);
                cmadd(acc[jo][1], a1, w);
            }
        }
    } else {
        const float2* swp = (const float2*)sw;
        for (int i = 0; i < 20; i++){
            cplx a0 = inS[i][m];
            cplx a1 = inS[20 + i][m];
            const float2* wr = swp + base0 + (size_t)i * 20 * 3072;
            #pragma unroll
            for (int jo = 0; jo < 5; jo++){
                cplx w = wr[(size_t)jo * 3072];
                cmadd(acc[jo][0], a0, w);
                cmadd(acc[jo][1], a1, w);
            }
        }
    }
    const float s = 1.0f / 524288.0f;               // irfftn normalization folded here
    #pragma unroll
    for (int jo = 0; jo < 5; jo++){
        int o = og * 5 + jo;
        #pragma unroll
        for (int b = 0; b < 2; b++){
            cplx v = acc[jo][b]; v.x *= s; v.y *= s;
            Ct[((size_t)(b * 20 + o) * 256 + mx * 16 + my) * 96 + zh * 48 + m] = v;
        }
    }
}

// ------------------------------------------------- inverse X + Y
// Ct[bo][mx][my][mz][k4] -> D[bo][x][y][mz][k4]
__global__ __launch_bounds__(256) void k_invXY(const cplx* __restrict__ Ct, cplx* __restrict__ D){
    const int kh = blockIdx.x, mz = blockIdx.y, bo = blockIdx.z;
    __shared__ cplx inS[16][16][3];
    __shared__ cplx midY[16][32][3];
    __shared__ cplx tw[16][32];
    const int tid = threadIdx.x;
    for (int i = tid; i < 512; i += 256){
        int m = i >> 5, p = i & 31;
        float s, c; sincosf(TWO_PI_32 * (float)((freqm(m) * p) & 31), &s, &c);
        tw[m][p] = make_float2(c, s);
    }
    for (int i = tid; i < 768; i += 256){
        int k = i % 3, t2 = i / 3;
        int my = t2 & 15, mx = t2 >> 4;
        inS[mx][my][k] = Ct[((size_t)bo * 256 + mx * 16 + my) * 96 + mz * 6 + kh * 3 + k];
    }
    __syncthreads();
    #pragma unroll
    for (int r = 0; r < 6; r++){
        int idx = tid + (r << 8);
        int k = idx % 3, t2 = idx / 3;
        int y = t2 & 31, mx = t2 >> 5;
        cplx acc = make_float2(0.f, 0.f);
        #pragma unroll
        for (int my = 0; my < 16; my++) cmadd(acc, inS[mx][my][k], tw[my][y]);
        midY[mx][y][k] = acc;
    }
    __syncthreads();
    #pragma unroll
    for (int r = 0; r < 4; r++){
        int idx = tid + (r << 8);
        int y = idx & 31, x = idx >> 5;
        cplx a0 = make_float2(0.f, 0.f), a1 = a0, a2 = a0;
        #pragma unroll
        for (int mx = 0; mx < 16; mx++){
            cplx t0 = tw[mx][x];
            cmadd(a0, midY[mx][y][0], t0);
            cmadd(a1, midY[mx][y][1], t0);
            cmadd(a2, midY[mx][y][2], t0);
        }
        size_t base = ((size_t)bo * 1024 + x * 32 + y) * 96 + mz * 6 + kh * 3;
        D[base] = a0; D[base + 1] = a1; D[base + 2] = a2;
    }
}

// ------------------------------------------------- inverse Z + irfft T + pointwise + gelu
template<int GELU>
__global__ __launch_bounds__(256) void k_invZT(const int* __restrict__ flag,
                                               const cplx* __restrict__ D, float* __restrict__ h,
                                               const void* __restrict__ ww, size_t woff,
                                               const void* __restrict__ wbv, size_t boff){
    const int bf = flag[0];
    const int y = blockIdx.x, x = blockIdx.y, b = blockIdx.z;
    __shared__ cplx Dsh[20][96];
    __shared__ __align__(16) cplx E[20][32][6];
    __shared__ cplx twz[16][32];
    __shared__ __align__(16) float swwT[400];   // transposed: [i][o]
    __shared__ float swb[20];
    const int tid = threadIdx.x;
    for (int i = tid; i < 512; i += 256){
        int m = i >> 5, z = i & 31;
        float s, c; sincosf(TWO_PI_32 * (float)((freqm(m) * z) & 31), &s, &c);
        twz[m][z] = make_float2(c, s);
    }
    for (int i = tid; i < 400; i += 256){
        int o = i / 20, ii = i % 20;
        swwT[ii * 20 + o] = LDR(ww, woff + i, bf);
    }
    if (tid < 20) swb[tid] = LDR(wbv, boff + tid, bf);
    for (int i = tid; i < 1920; i += 256){
        int o = i / 96, m = i % 96;
        Dsh[o][m] = D[((size_t)(b * 20 + o) * 1024 + x * 32 + y) * 96 + m];
    }
    __syncthreads();
    #pragma unroll
    for (int r = 0; r < 15; r++){
        int idx = tid + (r << 8);
        int k = idx % 6, t2 = idx / 6;
        int z = t2 & 31, o = t2 >> 5;
        cplx acc = make_float2(0.f, 0.f);
        #pragma unroll
        for (int mz = 0; mz < 16; mz++) cmadd(acc, Dsh[o][mz * 6 + k], twz[mz][z]);
        E[o][z][k] = acc;
    }
    __syncthreads();
    const int t  = tid & 15;
    const int z0 = tid >> 4;
    const int z1 = z0 + 16;
    float ct[6], st[6];
    ct[0] = 1.f; st[0] = 0.f;
    #pragma unroll
    for (int k = 1; k < 6; k++){
        sincosf(TWO_PI_16 * (float)((k * t) & 15), &st[k], &ct[k]);
    }
    float p0[20], p1[20];
    #pragma unroll
    for (int o = 0; o < 20; o++){ p0[o] = 0.f; p1[o] = 0.f; }
    const size_t hb = ((size_t)b * 20 * 1024 + x * 32 + y) * 512 + tid;
    for (int i = 0; i < 20; i++){
        float v0 = h[hb + (size_t)i * SPAT];
        float v1 = h[hb + (size_t)i * SPAT + 256];
        #pragma unroll
        for (int oc = 0; oc < 5; oc++){
            float4 w = *(const float4*)&swwT[i * 20 + oc * 4];
            p0[oc*4+0] = fmaf(v0, w.x, p0[oc*4+0]);
            p0[oc*4+1] = fmaf(v0, w.y, p0[oc*4+1]);
            p0[oc*4+2] = fmaf(v0, w.z, p0[oc*4+2]);
            p0[oc*4+3] = fmaf(v0, w.w, p0[oc*4+3]);
            p1[oc*4+0] = fmaf(v1, w.x, p1[oc*4+0]);
            p1[oc*4+1] = fmaf(v1, w.y, p1[oc*4+1]);
            p1[oc*4+2] = fmaf(v1, w.z, p1[oc*4+2]);
            p1[oc*4+3] = fmaf(v1, w.w, p1[oc*4+3]);
        }
    }
    #pragma unroll
    for (int o = 0; o < 20; o++){
        const float4* e0 = (const float4*)&E[o][z0][0];
        float4 a = e0[0], bq = e0[1], cq = e0[2];
        float v = a.x + 2.f * (a.z * ct[1] - a.w * st[1] + bq.x * ct[2] - bq.y * st[2]
                             + bq.z * ct[3] - bq.w * st[3] + cq.x * ct[4] - cq.y * st[4]
                             + cq.z * ct[5] - cq.w * st[5]);
        v += p0[o] + swb[o];
        if (GELU) v = gelu_f(v);
        h[hb + (size_t)o * SPAT] = v;

        const float4* e1 = (const float4*)&E[o][z1][0];
        a = e1[0]; bq = e1[1]; cq = e1[2];
        float v2 = a.x + 2.f * (a.z * ct[1] - a.w * st[1] + bq.x * ct[2] - bq.y * st[2]
                              + bq.z * ct[3] - bq.w * st[3] + cq.x * ct[4] - cq.y * st[4]
                              + cq.z * ct[5] - cq.w * st[5]);
        v2 += p1[o] + swb[o];
        if (GELU) v2 = gelu_f(v2);
        h[hb + (size_t)o * SPAT + 256] = v2;
    }
}

// ---------------------------------------------------------------- fc1 (gelu) + fc2 head
__global__ __launch_bounds__(256) void k_fc12(const int* __restrict__ flag,
                                              const float* __restrict__ h,
                                              const void* __restrict__ w1,
                                              const void* __restrict__ b1,
                                              const void* __restrict__ w2,
                                              const void* __restrict__ b2,
                                              void* __restrict__ out){
    const int bf = flag[0];
    __shared__ __align__(16) float s1[2560];
    __shared__ __align__(16) float sb1[128];
    __shared__ __align__(16) float s2[128];
    const int tid = threadIdx.x;
    for (int i = tid; i < 2560; i += 256) s1[i] = LDR(w1, i, bf);
    if (tid < 128){ sb1[tid] = LDR(b1, tid, bf); s2[tid] = LDR(w2, tid, bf); }
    __syncthreads();
    const int base = blockIdx.x * 256 + tid;
    float hi[4][20];
    #pragma unroll
    for (int q = 0; q < 4; q++){
        int p = base + (q << 18);
        int b = p >> 19, rem = p & (SPAT - 1);
        size_t hbq = (size_t)b * 20 * SPAT + rem;
        #pragma unroll
        for (int i = 0; i < 20; i++) hi[q][i] = h[hbq + (size_t)i * SPAT];
    }
    float acc[4] = {0.f, 0.f, 0.f, 0.f};
    const float fb2 = LDR(b2, 0, bf);
    for (int jc = 0; jc < 32; jc++){
        float4 bb = *(const float4*)&sb1[jc * 4];
        float v[4][4];
        #pragma unroll
        for (int q = 0; q < 4; q++){ v[q][0] = bb.x; v[q][1] = bb.y; v[q][2] = bb.z; v[q][3] = bb.w; }
        #pragma unroll
        for (int i = 0; i < 20; i++){
            float4 w = *(const float4*)&s1[i * 128 + jc * 4];
            #pragma unroll
            for (int q = 0; q < 4; q++){
                v[q][0] = fmaf(hi[q][i], w.x, v[q][0]);
                v[q][1] = fmaf(hi[q][i], w.y, v[q][1]);
                v[q][2] = fmaf(hi[q][i], w.z, v[q][2]);
                v[q][3] = fmaf(hi[q][i], w.w, v[q][3]);
            }
        }
        float4 w2v = *(const float4*)&s2[jc * 4];
        #pragma unroll
        for (int q = 0; q < 4; q++){
            acc[q] = fmaf(gelu_f(v[q][0]), w2v.x, acc[q]);
            acc[q] = fmaf(gelu_f(v[q][1]), w2v.y, acc[q]);
            acc[q] = fmaf(gelu_f(v[q][2]), w2v.z, acc[q]);
            acc[q] = fmaf(gelu_f(v[q][3]), w2v.w, acc[q]);
        }
    }
    #pragma unroll
    for (int q = 0; q < 4; q++) STR(out, base + (q << 18), acc[q] + fb2, bf);
}

extern "C" void kernel_launch(void* const* d_in, const int* in_sizes, int n_in,
                              void* d_out, int out_size, void* d_ws, size_t ws_size,
                              hipStream_t stream) {
    (void)in_sizes; (void)out_size;
    if (n_in < 10) return;
    if (ws_size < (size_t)WS_NEED) return;   // distinguishable failure: out stays 0 -> absmax 0.1035
    const void* x    = d_in[0];
    const void* fc0w = d_in[1];
    const void* fc0b = d_in[2];
    const void* sw   = d_in[3];
    const void* ww   = d_in[4];
    const void* wb   = d_in[5];
    const void* fc1w = d_in[6];
    const void* fc1b = d_in[7];
    const void* fc2w = d_in[8];
    const void* fc2b = d_in[9];

    char* ws = (char*)d_ws;
    float* h   = (float*)(ws + H_OFF);
    cplx*  A   = (cplx*)(ws + A_OFF);
    cplx*  Bt  = (cplx*)(ws + BT_OFF);
    cplx*  Ct  = (cplx*)(ws + CT_OFF);
    cplx*  Dd  = A;                          // A dead after fwdXY; reuse for D
    int*   flag = (int*)(ws + FLAG_OFF);

    k_detect<<<1, 64, 0, stream>>>((const unsigned short*)x, flag);
    k_fc0<<<4096, 256, 0, stream>>>(flag, x, fc0w, fc0b, h);
    for (int l = 0; l < 4; l++){
        size_t sw_off = (size_t)l * 9830400;   // complex elements per layer
        size_t ww_off = (size_t)l * 400;
        size_t wb_off = (size_t)l * 20;
        k_fwdTZ<<<dim3(4, 32, 40), 256, 0, stream>>>(h, A);
        k_fwdXY<<<dim3(2, 16, 40), 256, 0, stream>>>(A, Bt);
        k_mix<<<dim3(8, 8, 8), 192, 0, stream>>>(flag, Bt, sw, sw_off, Ct);
        k_invXY<<<dim3(2, 16, 40), 256, 0, stream>>>(Ct, Dd);
        if (l < 3) k_invZT<1><<<dim3(32, 32, 2), 256, 0, stream>>>(flag, Dd, h, ww, ww_off, wb, wb_off);
        else       k_invZT<0><<<dim3(32, 32, 2), 256, 0, stream>>>(flag, Dd, h, ww, ww_off, wb, wb_off);
    }
    k_fc12<<<1024, 256, 0, stream>>>(flag, h, fc1w, fc1b, fc2w, fc2b, d_out);
}

// Round 5
// 1517.037 us; speedup vs baseline: 1.2171x; 1.2171x over previous
//
#include <hip/hip_runtime.h>

typedef float2 cplx;

#define SPAT 524288          // 32*32*32*16
#define TWO_PI_16 0.39269908169872414f
#define TWO_PI_32 0.19634954084936207f

// ws layout (bytes)
#define H_OFF   0u
#define A_OFF   83886080u
#define BT_OFF  (83886080u + 31457280u)
#define CT_OFF  (83886080u + 31457280u + 7864320u)
#define FLAG_OFF (83886080u + 31457280u + 7864320u + 7864320u)
#define WS_NEED (FLAG_OFF + 64u)

__device__ __forceinline__ float bf2f(unsigned short s){
    union { unsigned int u; float f; } v; v.u = ((unsigned int)s) << 16; return v.f;
}
__device__ __forceinline__ unsigned short f2bf(float f){
    union { float ff; unsigned int u; } v; v.ff = f;
    unsigned int u = v.u;
    u += 0x7fffu + ((u >> 16) & 1u);   // round-to-nearest-even
    return (unsigned short)(u >> 16);
}
__device__ __forceinline__ cplx bf2c(unsigned int p){
    union { unsigned int u; float f; } a, b;
    a.u = p << 16; b.u = p & 0xffff0000u;
    cplx r; r.x = a.f; r.y = b.f; return r;
}
// runtime-dtype loads/stores (bf=1: bf16 storage, bf=0: fp32 storage)
__device__ __forceinline__ float LDR(const void* p, size_t i, int bf){
    return bf ? bf2f(((const unsigned short*)p)[i]) : ((const float*)p)[i];
}
__device__ __forceinline__ void STR(void* p, size_t i, float v, int bf){
    if (bf) ((unsigned short*)p)[i] = f2bf(v);
    else    ((float*)p)[i] = v;
}
__device__ __forceinline__ void cmadd(cplx& d, const cplx a, const cplx b){
    d.x = fmaf(a.x, b.x, d.x);
    d.x = fmaf(-a.y, b.y, d.x);
    d.y = fmaf(a.x, b.y, d.y);
    d.y = fmaf(a.y, b.x, d.y);
}
__device__ __forceinline__ int freqm(int m){ return m + ((m >> 3) << 4); } // 0..7 -> 0..7, 8..15 -> 24..31
__device__ __forceinline__ float gelu_f(float v){
    return 0.5f * v * (1.0f + erff(v * 0.7071067811865475f));
}

// ------------------------------------------------- dtype detector (1 block, 1 wave, no atomics)
__global__ void k_detect(const unsigned short* __restrict__ x, int* __restrict__ flag){
    __shared__ int cnts[64];
    const int tid = threadIdx.x;
    int cnt = 0;
    for (int j = tid; j < 512; j += 64){
        unsigned short u = x[2 * j];
        unsigned int e = (u >> 7) & 0xFFu;
        if (e < 27u || e > 160u) cnt++;    // |bf16| outside [~1e-30, ~1e10] incl inf/nan/denorm
    }
    cnts[tid] = cnt;
    __syncthreads();
    if (tid == 0){
        int s = 0;
        for (int i = 0; i < 64; i++) s += cnts[i];
        flag[0] = (s > 64) ? 0 : 1;        // many wild exponents -> fp32
    }
}

// ---------------------------------------------------------------- fc0 lift
__global__ __launch_bounds__(256) void k_fc0(const int* __restrict__ flag,
                                             const void* __restrict__ x,
                                             const void* __restrict__ w,
                                             const void* __restrict__ bias,
                                             float* __restrict__ h){
    const int bf = flag[0];
    __shared__ float sw[100];
    __shared__ float sb[20];
    const int tid = threadIdx.x;
    if (tid < 100) sw[tid] = LDR(w, tid, bf);
    if (tid < 20)  sb[tid] = LDR(bias, tid, bf);
    __syncthreads();
    const int p = blockIdx.x * 256 + tid;          // 0 .. 1048575
    const int b = p >> 19;
    const int rem = p & (SPAT - 1);
    float xi[5];
    #pragma unroll
    for (int i = 0; i < 5; i++) xi[i] = LDR(x, (size_t)p * 5 + i, bf);
    const size_t ob = (size_t)b * 20 * SPAT + rem;
    #pragma unroll
    for (int c = 0; c < 20; c++){
        float acc = sb[c];
        #pragma unroll
        for (int i = 0; i < 5; i++) acc = fmaf(xi[i], sw[i * 20 + c], acc);
        h[ob + (size_t)c * SPAT] = acc;
    }
}

// ------------------------------------------------- forward T (rfft, 6 bins) + Z (16 bins)
// h[b,c,x,y,z,t] -> A[bc][mz(16)][k4(6)][x][y]
__global__ __launch_bounds__(256) void k_fwdTZ(const float* __restrict__ h, cplx* __restrict__ A){
    const int bc = blockIdx.z;           // 0..39
    const int x  = blockIdx.y;           // 0..31
    const int y0 = blockIdx.x << 3;      // y tile of 8
    __shared__ float sinp[8][32][17];
    __shared__ cplx  mid[8][193];
    __shared__ cplx  twT[6][16];
    __shared__ cplx  twZ[16][32];
    const int tid = threadIdx.x;
    for (int i = tid; i < 96; i += 256){
        int k = i >> 4, t = i & 15;
        float s, c; sincosf(-TWO_PI_16 * (float)((k * t) & 15), &s, &c);
        twT[k][t] = make_float2(c, s);
    }
    for (int i = tid; i < 512; i += 256){
        int m = i >> 5, z = i & 31;
        float s, c; sincosf(-TWO_PI_32 * (float)((freqm(m) * z) & 31), &s, &c);
        twZ[m][z] = make_float2(c, s);
    }
    const float* src = h + ((size_t)bc * 1024 + x * 32 + y0) * 512;
    for (int i = tid; i < 4096; i += 256){
        int line = i >> 9, zt = i & 511;
        sinp[line][zt >> 4][zt & 15] = src[i];
    }
    __syncthreads();
    #pragma unroll
    for (int r = 0; r < 6; r++){
        int idx = tid + (r << 8);
        int k4 = idx % 6;
        int zz = (idx / 6) & 31;
        int line = idx / 192;
        cplx acc = make_float2(0.f, 0.f);
        #pragma unroll
        for (int t = 0; t < 16; t++){
            float v = sinp[line][zz][t];
            acc.x = fmaf(v, twT[k4][t].x, acc.x);
            acc.y = fmaf(v, twT[k4][t].y, acc.y);
        }
        mid[line][zz * 6 + k4] = acc;
    }
    __syncthreads();
    #pragma unroll
    for (int r = 0; r < 3; r++){
        int idx = tid + (r << 8);
        int line = idx & 7;
        int mzk = idx >> 3;
        int k4 = mzk % 6;
        int mz = mzk / 6;
        cplx acc = make_float2(0.f, 0.f);
        #pragma unroll
        for (int zz = 0; zz < 32; zz++)
            cmadd(acc, mid[line][zz * 6 + k4], twZ[mz][zz]);
        A[((size_t)bc * 96 + mz * 6 + k4) * 1024 + x * 32 + y0 + line] = acc;
    }
}

// ------------------------------------------------- forward Y + X
// A[bc][mz][k4][x][y] -> Bt[b*20+c][mx][my][mz][k4]
__global__ __launch_bounds__(256) void k_fwdXY(const cplx* __restrict__ A, cplx* __restrict__ Bt){
    const int kh = blockIdx.x;
    const int mz = blockIdx.y;
    const int bc = blockIdx.z;
    __shared__ cplx inb[3][1057];
    __shared__ cplx midY[3][545];
    __shared__ cplx tw[16][32];
    const int tid = threadIdx.x;
    for (int i = tid; i < 512; i += 256){
        int m = i >> 5, p = i & 31;
        float s, c; sincosf(-TWO_PI_32 * (float)((freqm(m) * p) & 31), &s, &c);
        tw[m][p] = make_float2(c, s);
    }
    const cplx* src = A + ((size_t)bc * 96 + mz * 6 + kh * 3) * 1024;
    for (int i = tid; i < 3072; i += 256){
        int k = i >> 10, rem = i & 1023;
        inb[k][(rem >> 5) * 33 + (rem & 31)] = src[i];
    }
    __syncthreads();
    #pragma unroll
    for (int r = 0; r < 6; r++){
        int idx = tid + (r << 8);
        int k = idx % 3, t2 = idx / 3;
        int my = t2 & 15, xx = t2 >> 4;
        cplx acc = make_float2(0.f, 0.f);
        #pragma unroll
        for (int yy = 0; yy < 32; yy++) cmadd(acc, inb[k][xx * 33 + yy], tw[my][yy]);
        midY[k][xx * 17 + my] = acc;
    }
    __syncthreads();
    #pragma unroll
    for (int r = 0; r < 3; r++){
        int idx = tid + (r << 8);
        int k = idx % 3, t2 = idx / 3;
        int my = t2 & 15, mx = t2 >> 4;
        cplx acc = make_float2(0.f, 0.f);
        #pragma unroll
        for (int xx = 0; xx < 32; xx++) cmadd(acc, midY[k][xx * 17 + my], tw[mx][xx]);
        Bt[((size_t)bc * 256 + mx * 16 + my) * 96 + mz * 6 + kh * 3 + k] = acc;
    }
}

// ------------------------------------------------- per-mode channel mix (20x20 complex)
__global__ __launch_bounds__(192) void k_mix(const int* __restrict__ flag,
                                             const cplx* __restrict__ Bt,
                                             const void* __restrict__ sw, size_t loff,
                                             cplx* __restrict__ Ct){
    const int bf = flag[0];
    const int j2 = blockIdx.x, j1 = blockIdx.y, oct = blockIdx.z;
    const int xh = oct >> 2, yh = (oct >> 1) & 1, zh = oct & 1;
    const int mx = xh * 8 + j1, my = yh * 8 + j2;
    __shared__ cplx inS[40][48];
    const int tid = threadIdx.x;
    for (int idx = tid; idx < 1920; idx += 192){
        int m = idx % 48, row = idx / 48;
        inS[row][m] = Bt[((size_t)row * 256 + mx * 16 + my) * 96 + zh * 48 + m];
    }
    __syncthreads();
    const int m = tid % 48, og = tid / 48;
    cplx acc[5][2];
    #pragma unroll
    for (int jo = 0; jo < 5; jo++){
        acc[jo][0] = make_float2(0.f, 0.f);
        acc[jo][1] = make_float2(0.f, 0.f);
    }
    const size_t base0 = loff + (size_t)(oct * 20) * 20 * 3072
                              + (size_t)(og * 5) * 3072 + (j1 * 8 + j2) * 48 + m;
    if (bf){
        const unsigned int* swp = (const unsigned int*)sw;
        for (int i = 0; i < 20; i++){
            cplx a0 = inS[i][m];
            cplx a1 = inS[20 + i][m];
            const unsigned int* wr = swp + base0 + (size_t)i * 20 * 3072;
            #pragma unroll
            for (int jo = 0; jo < 5; jo++){
                cplx w = bf2c(wr[(size_t)jo * 3072]);
                cmadd(acc[jo][0], a0, w);
                cmadd(acc[jo][1], a1, w);
            }
        }
    } else {
        const float2* swp = (const float2*)sw;
        for (int i = 0; i < 20; i++){
            cplx a0 = inS[i][m];
            cplx a1 = inS[20 + i][m];
            const float2* wr = swp + base0 + (size_t)i * 20 * 3072;
            #pragma unroll
            for (int jo = 0; jo < 5; jo++){
                cplx w = wr[(size_t)jo * 3072];
                cmadd(acc[jo][0], a0, w);
                cmadd(acc[jo][1], a1, w);
            }
        }
    }
    const float s = 1.0f / 524288.0f;               // irfftn normalization folded here
    #pragma unroll
    for (int jo = 0; jo < 5; jo++){
        int o = og * 5 + jo;
        #pragma unroll
        for (int b = 0; b < 2; b++){
            cplx v = acc[jo][b]; v.x *= s; v.y *= s;
            Ct[((size_t)(b * 20 + o) * 256 + mx * 16 + my) * 96 + zh * 48 + m] = v;
        }
    }
}

// ------------------------------------------------- inverse X + Y
// Ct[bo][mx][my][mz][k4] -> D[bo][x][y][mz][k4]
__global__ __launch_bounds__(256) void k_invXY(const cplx* __restrict__ Ct, cplx* __restrict__ D){
    const int kh = blockIdx.x, mz = blockIdx.y, bo = blockIdx.z;
    __shared__ cplx inS[16][16][3];
    __shared__ cplx midY[16][32][3];
    __shared__ cplx tw[16][32];
    const int tid = threadIdx.x;
    for (int i = tid; i < 512; i += 256){
        int m = i >> 5, p = i & 31;
        float s, c; sincosf(TWO_PI_32 * (float)((freqm(m) * p) & 31), &s, &c);
        tw[m][p] = make_float2(c, s);
    }
    for (int i = tid; i < 768; i += 256){
        int k = i % 3, t2 = i / 3;
        int my = t2 & 15, mx = t2 >> 4;
        inS[mx][my][k] = Ct[((size_t)bo * 256 + mx * 16 + my) * 96 + mz * 6 + kh * 3 + k];
    }
    __syncthreads();
    #pragma unroll
    for (int r = 0; r < 6; r++){
        int idx = tid + (r << 8);
        int k = idx % 3, t2 = idx / 3;
        int y = t2 & 31, mx = t2 >> 5;
        cplx acc = make_float2(0.f, 0.f);
        #pragma unroll
        for (int my = 0; my < 16; my++) cmadd(acc, inS[mx][my][k], tw[my][y]);
        midY[mx][y][k] = acc;
    }
    __syncthreads();
    #pragma unroll
    for (int r = 0; r < 4; r++){
        int idx = tid + (r << 8);
        int y = idx & 31, x = idx >> 5;
        cplx a0 = make_float2(0.f, 0.f), a1 = a0, a2 = a0;
        #pragma unroll
        for (int mx = 0; mx < 16; mx++){
            cplx t0 = tw[mx][x];
            cmadd(a0, midY[mx][y][0], t0);
            cmadd(a1, midY[mx][y][1], t0);
            cmadd(a2, midY[mx][y][2], t0);
        }
        size_t base = ((size_t)bo * 1024 + x * 32 + y) * 96 + mz * 6 + kh * 3;
        D[base] = a0; D[base + 1] = a1; D[base + 2] = a2;
    }
}

// ------------------------------------------------- inverse Z + irfft T + pointwise + gelu
// 512 threads, one (z,t) point/thread. VGPR cap 128 (launch_bounds 512,4) -> 16 waves/CU.
template<int GELU>
__global__ __launch_bounds__(512, 4) void k_invZT(const int* __restrict__ flag,
                                               const cplx* __restrict__ D, float* __restrict__ h,
                                               const void* __restrict__ ww, size_t woff,
                                               const void* __restrict__ wbv, size_t boff){
    const int bf = flag[0];
    const int y = blockIdx.x, x = blockIdx.y, b = blockIdx.z;
    __shared__ cplx Dsh[20][96];
    __shared__ __align__(16) cplx E[20][32][6];
    __shared__ cplx twz[16][32];
    __shared__ __align__(16) float sww[400];    // [o][i]  (o-major: float4 i-reads per o)
    __shared__ float swb[20];
    const int tid = threadIdx.x;
    if (tid < 512){
        int m = tid >> 5, z = tid & 31;
        float s, c; sincosf(TWO_PI_32 * (float)((freqm(m) * z) & 31), &s, &c);
        twz[m][z] = make_float2(c, s);
    }
    if (tid < 400) sww[tid] = LDR(ww, woff + tid, bf);   // ww[l][o][i] row-major = direct copy
    if (tid < 20)  swb[tid] = LDR(wbv, boff + tid, bf);
    for (int i = tid; i < 1920; i += 512){
        int o = i / 96, m = i % 96;
        Dsh[o][m] = D[((size_t)(b * 20 + o) * 1024 + x * 32 + y) * 96 + m];
    }
    __syncthreads();
    // inv-Z: E[o][z][k] : 3840 outputs over 512 threads
    #pragma unroll
    for (int r = 0; r < 8; r++){
        int idx = tid + (r << 9);
        if (idx < 3840){
            int k = idx % 6, t2 = idx / 6;
            int z = t2 & 31, o = t2 >> 5;
            cplx acc = make_float2(0.f, 0.f);
            #pragma unroll
            for (int mz = 0; mz < 16; mz++) cmadd(acc, Dsh[o][mz * 6 + k], twz[mz][z]);
            E[o][z][k] = acc;
        }
    }
    __syncthreads();
    // per-point phase: thread owns (z,t) = (tid>>4, tid&15)
    const int t = tid & 15;
    const int z = tid >> 4;
    float ct[6], st[6];
    ct[0] = 1.f; st[0] = 0.f;
    #pragma unroll
    for (int k = 1; k < 6; k++){
        sincosf(TWO_PI_16 * (float)((k * t) & 15), &st[k], &ct[k]);
    }
    const size_t hb = ((size_t)b * 20 * 1024 + x * 32 + y) * 512 + tid;
    float hi[20];
    #pragma unroll
    for (int i = 0; i < 20; i++) hi[i] = h[hb + (size_t)i * SPAT];
    #pragma unroll
    for (int o = 0; o < 20; o++){
        const float4* e = (const float4*)&E[o][z][0];
        float4 a = e[0], bq = e[1], cq = e[2];
        float v = a.x + 2.f * (a.z * ct[1] - a.w * st[1] + bq.x * ct[2] - bq.y * st[2]
                             + bq.z * ct[3] - bq.w * st[3] + cq.x * ct[4] - cq.y * st[4]
                             + cq.z * ct[5] - cq.w * st[5]);
        const float4* wr = (const float4*)&sww[o * 20];
        float4 w0 = wr[0], w1 = wr[1], w2 = wr[2], w3 = wr[3], w4 = wr[4];
        float p = swb[o];
        p = fmaf(hi[ 0], w0.x, p); p = fmaf(hi[ 1], w0.y, p);
        p = fmaf(hi[ 2], w0.z, p); p = fmaf(hi[ 3], w0.w, p);
        p = fmaf(hi[ 4], w1.x, p); p = fmaf(hi[ 5], w1.y, p);
        p = fmaf(hi[ 6], w1.z, p); p = fmaf(hi[ 7], w1.w, p);
        p = fmaf(hi[ 8], w2.x, p); p = fmaf(hi[ 9], w2.y, p);
        p = fmaf(hi[10], w2.z, p); p = fmaf(hi[11], w2.w, p);
        p = fmaf(hi[12], w3.x, p); p = fmaf(hi[13], w3.y, p);
        p = fmaf(hi[14], w3.z, p); p = fmaf(hi[15], w3.w, p);
        p = fmaf(hi[16], w4.x, p); p = fmaf(hi[17], w4.y, p);
        p = fmaf(hi[18], w4.z, p); p = fmaf(hi[19], w4.w, p);
        v += p;
        if (GELU) v = gelu_f(v);
        h[hb + (size_t)o * SPAT] = v;
    }
}

// ---------------------------------------------------------------- fc1 (gelu) + fc2 head
__global__ __launch_bounds__(256) void k_fc12(const int* __restrict__ flag,
                                              const float* __restrict__ h,
                                              const void* __restrict__ w1,
                                              const void* __restrict__ b1,
                                              const void* __restrict__ w2,
                                              const void* __restrict__ b2,
                                              void* __restrict__ out){
    const int bf = flag[0];
    __shared__ __align__(16) float s1[2560];
    __shared__ __align__(16) float sb1[128];
    __shared__ __align__(16) float s2[128];
    const int tid = threadIdx.x;
    for (int i = tid; i < 2560; i += 256) s1[i] = LDR(w1, i, bf);
    if (tid < 128){ sb1[tid] = LDR(b1, tid, bf); s2[tid] = LDR(w2, tid, bf); }
    __syncthreads();
    const int base = blockIdx.x * 256 + tid;
    float hi[4][20];
    #pragma unroll
    for (int q = 0; q < 4; q++){
        int p = base + (q << 18);
        int b = p >> 19, rem = p & (SPAT - 1);
        size_t hbq = (size_t)b * 20 * SPAT + rem;
        #pragma unroll
        for (int i = 0; i < 20; i++) hi[q][i] = h[hbq + (size_t)i * SPAT];
    }
    float acc[4] = {0.f, 0.f, 0.f, 0.f};
    const float fb2 = LDR(b2, 0, bf);
    for (int jc = 0; jc < 32; jc++){
        float4 bb = *(const float4*)&sb1[jc * 4];
        float v[4][4];
        #pragma unroll
        for (int q = 0; q < 4; q++){ v[q][0] = bb.x; v[q][1] = bb.y; v[q][2] = bb.z; v[q][3] = bb.w; }
        #pragma unroll
        for (int i = 0; i < 20; i++){
            float4 w = *(const float4*)&s1[i * 128 + jc * 4];
            #pragma unroll
            for (int q = 0; q < 4; q++){
                v[q][0] = fmaf(hi[q][i], w.x, v[q][0]);
                v[q][1] = fmaf(hi[q][i], w.y, v[q][1]);
                v[q][2] = fmaf(hi[q][i], w.z, v[q][2]);
                v[q][3] = fmaf(hi[q][i], w.w, v[q][3]);
            }
        }
        float4 w2v = *(const float4*)&s2[jc * 4];
        #pragma unroll
        for (int q = 0; q < 4; q++){
            acc[q] = fmaf(gelu_f(v[q][0]), w2v.x, acc[q]);
            acc[q] = fmaf(gelu_f(v[q][1]), w2v.y, acc[q]);
            acc[q] = fmaf(gelu_f(v[q][2]), w2v.z, acc[q]);
            acc[q] = fmaf(gelu_f(v[q][3]), w2v.w, acc[q]);
        }
    }
    #pragma unroll
    for (int q = 0; q < 4; q++) STR(out, base + (q << 18), acc[q] + fb2, bf);
}

extern "C" void kernel_launch(void* const* d_in, const int* in_sizes, int n_in,
                              void* d_out, int out_size, void* d_ws, size_t ws_size,
                              hipStream_t stream) {
    (void)in_sizes; (void)out_size;
    if (n_in < 10) return;
    if (ws_size < (size_t)WS_NEED) return;   // distinguishable failure: out stays 0 -> absmax 0.1035
    const void* x    = d_in[0];
    const void* fc0w = d_in[1];
    const void* fc0b = d_in[2];
    const void* sw   = d_in[3];
    const void* ww   = d_in[4];
    const void* wb   = d_in[5];
    const void* fc1w = d_in[6];
    const void* fc1b = d_in[7];
    const void* fc2w = d_in[8];
    const void* fc2b = d_in[9];

    char* ws = (char*)d_ws;
    float* h   = (float*)(ws + H_OFF);
    cplx*  A   = (cplx*)(ws + A_OFF);
    cplx*  Bt  = (cplx*)(ws + BT_OFF);
    cplx*  Ct  = (cplx*)(ws + CT_OFF);
    cplx*  Dd  = A;                          // A dead after fwdXY; reuse for D
    int*   flag = (int*)(ws + FLAG_OFF);

    k_detect<<<1, 64, 0, stream>>>((const unsigned short*)x, flag);
    k_fc0<<<4096, 256, 0, stream>>>(flag, x, fc0w, fc0b, h);
    for (int l = 0; l < 4; l++){
        size_t sw_off = (size_t)l * 9830400;   // complex elements per layer
        size_t ww_off = (size_t)l * 400;
        size_t wb_off = (size_t)l * 20;
        k_fwdTZ<<<dim3(4, 32, 40), 256, 0, stream>>>(h, A);
        k_fwdXY<<<dim3(2, 16, 40), 256, 0, stream>>>(A, Bt);
        k_mix<<<dim3(8, 8, 8), 192, 0, stream>>>(flag, Bt, sw, sw_off, Ct);
        k_invXY<<<dim3(2, 16, 40), 256, 0, stream>>>(Ct, Dd);
        if (l < 3) k_invZT<1><<<dim3(32, 32, 2), 512, 0, stream>>>(flag, Dd, h, ww, ww_off, wb, wb_off);
        else       k_invZT<0><<<dim3(32, 32, 2), 512, 0, stream>>>(flag, Dd, h, ww, ww_off, wb, wb_off);
    }
    k_fc12<<<1024, 256, 0, stream>>>(flag, h, fc1w, fc1b, fc2w, fc2b, d_out);
}